// Round 2
// baseline (1647.223 us; speedup 1.0000x reference)
//
#include <hip/hip_runtime.h>
#include <stdint.h>

// ---------- types / helpers ----------
typedef __attribute__((ext_vector_type(8))) short s16x8;   // 8 bf16 (4 VGPR) MFMA operand
typedef __attribute__((ext_vector_type(4))) float f32x4;   // MFMA accumulator

__device__ __forceinline__ float bf2f(unsigned short u) {
  union { unsigned int i; float f; } x; x.i = ((unsigned int)u) << 16; return x.f;
}
__device__ __forceinline__ unsigned short f2bf(float f) {
  union { float f; unsigned int i; } x; x.f = f;
  return (unsigned short)((x.i + 0x7FFFu + ((x.i >> 16) & 1u)) >> 16);  // RNE
}
__device__ __forceinline__ void gload16(const unsigned short* g, unsigned short* l) {
  __builtin_amdgcn_global_load_lds((const __attribute__((address_space(1))) void*)g,
                                   (__attribute__((address_space(3))) void*)l, 16, 0, 0);
}

// ---------- weight transpose + f32->bf16:  w[K][N] -> wt[N][K] ----------
__global__ void wtrans_kernel(const float* __restrict__ w, unsigned short* __restrict__ wt,
                              int K, int N) {
  __shared__ float tile[32][33];
  const int n0 = blockIdx.x * 32, k0 = blockIdx.y * 32;
  const int tx = threadIdx.x, ty = threadIdx.y;            // 32 x 8
  for (int r = 0; r < 32; r += 8)
    tile[ty + r][tx] = w[(size_t)(k0 + ty + r) * N + n0 + tx];
  __syncthreads();
  for (int r = 0; r < 32; r += 8)
    wt[(size_t)(n0 + ty + r) * K + k0 + tx] = f2bf(tile[tx][ty + r]);
}

// ---------- elementwise f32 -> bf16 (vectorized) ----------
__global__ void cvt_f32_bf16(const float* __restrict__ src, unsigned short* __restrict__ dst, int n4) {
  int i = blockIdx.x * blockDim.x + threadIdx.x;
  const int stride = gridDim.x * blockDim.x;
  for (; i < n4; i += stride) {
    float4 v = ((const float4*)src)[i];
    ushort4 o; o.x = f2bf(v.x); o.y = f2bf(v.y); o.z = f2bf(v.z); o.w = f2bf(v.w);
    ((ushort4*)dst)[i] = o;
  }
}

// ---------- bf16 MFMA GEMM: C[M][N](bf16) = epi(A[M][K] @ Bt[N][K]^T + bias) ----------
// AMODE 0: A direct row-major.  AMODE 1: virtual concat rows: r -> b=r/9,n=r%9; n<8: A(mem_bf)[b*8+n], else A2(inp_bf)[b]
// EPI 0: +bias          EPI 1: relu(+bias)
// EPI 3: sigmoid(+mg_b + ig_part[row/8][col] + (col<1024?input_bias:forget_bias))
// Grid is launched 1-D (nwg = tilesM*tilesN, nwg%8==0); XCD-bijective swizzle (T1)
// then decompose swizzled id into (tileN, tileM) with tileN fastest.
template<int AMODE, int EPI>
__global__ void __launch_bounds__(256)
gemm_bt(const unsigned short* __restrict__ A,
        const unsigned short* __restrict__ A2,
        const unsigned short* __restrict__ Bt,
        const float* __restrict__ bias,
        const unsigned short* __restrict__ igp,
        const float* __restrict__ sib,      // input_bias (device scalar)
        const float* __restrict__ sfb,      // forget_bias (device scalar)
        unsigned short* __restrict__ C,
        int tilesN, int N, int K)
{
  __shared__ __align__(16) unsigned short As[128 * 32];
  __shared__ __align__(16) unsigned short Bs[128 * 32];
  const int t = threadIdx.x;
  const int w = t >> 6, l = t & 63;

  // T1: XCD-aware bijective swizzle of the linear workgroup id (nwg % 8 == 0).
  const int nwg = gridDim.x;
  const int cpx = nwg >> 3;                          // chunks per XCD
  const int lid = blockIdx.x;
  const int wgid = (lid & 7) * cpx + (lid >> 3);
  const int bty = wgid / tilesN;                     // M-tile
  const int btx = wgid - bty * tilesN;               // N-tile
  const int brow = bty << 7, bcol = btx << 7;
  const int wr = w >> 1, wc = w & 1;                 // 2x2 wave grid, 64x64 each

  // staging map: pass p, wave w, lane l -> tile byte = (p*4+w)*1024 + l*16
  const unsigned short* ap[2];
  const unsigned short* bp[2];
  unsigned short* al[2];
  unsigned short* bl[2];
#pragma unroll
  for (int p0 = 0; p0 < 2; ++p0) {
    const int byteoff = ((p0 * 4 + w) << 10) + (l << 4);
    const int row = byteoff >> 6;                    // tile row (64B = 32 bf16 per row)
    const int ce  = (byteoff & 63) >> 1;             // k-element within row
    const int ar  = brow + row;
    if (AMODE == 0) {
      ap[p0] = A + (size_t)ar * K + ce;
    } else {
      const int bb = ar / 9;
      const int nn = ar - bb * 9;
      ap[p0] = (nn < 8 ? (A + ((size_t)(bb * 8 + nn)) * K) : (A2 + (size_t)bb * K)) + ce;
    }
    bp[p0] = Bt + (size_t)(bcol + row) * K + ce;
    al[p0] = As + ((p0 * 4 + w) << 9);               // wave-uniform LDS base (512 ushort = 1KB)
    bl[p0] = Bs + ((p0 * 4 + w) << 9);
  }

  f32x4 acc[4][4] = {};
  const int kiters = K >> 5;
  for (int kt = 0; kt < kiters; ++kt) {
#pragma unroll
    for (int p0 = 0; p0 < 2; ++p0) {
      gload16(ap[p0], al[p0]);
      gload16(bp[p0], bl[p0]);
      ap[p0] += 32; bp[p0] += 32;
    }
    __syncthreads();
    const int lr = l & 15, lk = (l >> 4) << 3;
    s16x8 af[4], bfr[4];
#pragma unroll
    for (int m = 0; m < 4; ++m)
      af[m] = *(const s16x8*)(As + ((wr * 64 + m * 16 + lr) << 5) + lk);
#pragma unroll
    for (int n = 0; n < 4; ++n)
      bfr[n] = *(const s16x8*)(Bs + ((wc * 64 + n * 16 + lr) << 5) + lk);
#pragma unroll
    for (int m = 0; m < 4; ++m)
#pragma unroll
      for (int n = 0; n < 4; ++n)
        acc[m][n] = __builtin_amdgcn_mfma_f32_16x16x32_bf16(af[m], bfr[n], acc[m][n], 0, 0, 0);
    __syncthreads();
  }

  float ib = 0.f, fb = 0.f;
  if constexpr (EPI == 3) { ib = sib[0]; fb = sfb[0]; }
  const int row0 = brow + wr * 64 + ((l >> 4) << 2);   // C/D: col=lane&15, row=(lane>>4)*4+j
  const int col0 = bcol + wc * 64 + (l & 15);
#pragma unroll
  for (int m = 0; m < 4; ++m) {
#pragma unroll
    for (int n = 0; n < 4; ++n) {
      const int col = col0 + n * 16;
      const float bv = bias[col];
#pragma unroll
      for (int j = 0; j < 4; ++j) {
        const int row = row0 + m * 16 + j;
        float x = acc[m][n][j] + bv;
        if constexpr (EPI == 1) x = fmaxf(x, 0.f);
        if constexpr (EPI == 3) {
          x += bf2f(igp[(size_t)(row >> 3) * 2048 + col]);
          x += (col < 1024) ? ib : fb;
          x = 1.f / (1.f + expf(-x));
        }
        C[(size_t)row * N + col] = f2bf(x);
      }
    }
  }
}

// ---------- fused: qkv-LN -> attention -> residual -> LN1 ----------
#define QROW 3080   // 3072 + 8 pad: breaks row-stride bank aliasing
__global__ void __launch_bounds__(256)
attn_fused(const unsigned short* __restrict__ qkv,     // [B*9][3072] bf16 (pre-LN)
           const float* __restrict__ g3, const float* __restrict__ b3,
           const float* __restrict__ memF,             // fp32 memory [B][8][1024]
           const float* __restrict__ g1, const float* __restrict__ b1,
           unsigned short* __restrict__ m1)            // out [B*8][1024] bf16
{
  __shared__ __align__(16) unsigned short sQ[9 * QROW];  // 55440 B
  __shared__ float sS[16][8][12];                        // 6144 B scores->probs
  __shared__ __align__(16) unsigned short sAtt[8 * 1024];// 16384 B
  const int b = blockIdx.x;
  const int t = threadIdx.x;
  const int wv = t >> 6, l = t & 63;

  // load 9x3072 bf16 tile (3456 x 16B)
  const unsigned short* src = qkv + (size_t)b * (9 * 3072);
  for (int i = t; i < 3456; i += 256) {
    const int r = i / 384;
    const int c = i - r * 384;
    ((uint4*)(sQ + r * QROW))[c] = ((const uint4*)src)[i];
  }
  __syncthreads();

  // LN each of 9 rows over 3072, normalize in place
  for (int r = wv; r < 9; r += 4) {
    float s = 0.f, s2 = 0.f;
    for (int i = l; i < 3072; i += 64) {
      const float x = bf2f(sQ[r * QROW + i]); s += x; s2 += x * x;
    }
#pragma unroll
    for (int o = 32; o; o >>= 1) { s += __shfl_xor(s, o); s2 += __shfl_xor(s2, o); }
    const float mean = s * (1.f / 3072.f);
    const float rstd = rsqrtf(s2 * (1.f / 3072.f) - mean * mean + 1e-5f);
    for (int i = l; i < 3072; i += 64) {
      const float x = bf2f(sQ[r * QROW + i]);
      sQ[r * QROW + i] = f2bf((x - mean) * rstd * g3[i] + b3[i]);
    }
  }
  __syncthreads();

  // scores: 16 heads x 8 q-rows x 9 k-rows (q rows 8.. not needed downstream)
  for (int idx = t; idx < 1152; idx += 256) {
    const int h = idx / 72;
    const int rem = idx - h * 72;
    const int n = rem / 9;
    const int m = rem - n * 9;
    const ushort4* q4 = (const ushort4*)(sQ + n * QROW + h * 192);
    const ushort4* k4 = (const ushort4*)(sQ + m * QROW + h * 192 + 64);
    float acc = 0.f;
#pragma unroll
    for (int d = 0; d < 16; ++d) {
      const ushort4 qa = q4[d], ka = k4[d];
      acc += bf2f(qa.x) * bf2f(ka.x) + bf2f(qa.y) * bf2f(ka.y)
           + bf2f(qa.z) * bf2f(ka.z) + bf2f(qa.w) * bf2f(ka.w);
    }
    sS[h][n][m] = acc * 0.125f;   // * HEAD^-0.5
  }
  __syncthreads();

  // softmax over m (9) for each (h,n)
  if (t < 128) {
    const int h = t >> 3, n = t & 7;
    float mx = -1e30f;
#pragma unroll
    for (int m = 0; m < 9; ++m) mx = fmaxf(mx, sS[h][n][m]);
    float p[9]; float sum = 0.f;
#pragma unroll
    for (int m = 0; m < 9; ++m) { p[m] = expf(sS[h][n][m] - mx); sum += p[m]; }
    const float inv = 1.f / sum;
#pragma unroll
    for (int m = 0; m < 9; ++m) sS[h][n][m] = p[m] * inv;
  }
  __syncthreads();

  // PV: attended[n][h*64+d], 2048 ushort4 outputs
  for (int o4 = t; o4 < 2048; o4 += 256) {
    const int n = o4 >> 8;
    const int rem = o4 & 255;
    const int h = rem >> 4;
    const int d4 = rem & 15;
    float a0 = 0, a1 = 0, a2 = 0, a3 = 0;
#pragma unroll
    for (int m = 0; m < 9; ++m) {
      const float pm = sS[h][n][m];
      const ushort4 vv = *(const ushort4*)(sQ + m * QROW + h * 192 + 128 + d4 * 4);
      a0 += pm * bf2f(vv.x); a1 += pm * bf2f(vv.y); a2 += pm * bf2f(vv.z); a3 += pm * bf2f(vv.w);
    }
    ushort4 ov; ov.x = f2bf(a0); ov.y = f2bf(a1); ov.z = f2bf(a2); ov.w = f2bf(a3);
    ((ushort4*)sAtt)[o4] = ov;
  }
  __syncthreads();

  // residual (original fp32 memory) + LN1, rows 0..7 -> m1 bf16
  const float* memb = memF + (size_t)b * 8192;
  for (int n = wv; n < 8; n += 4) {
    float xs[16]; float s = 0.f, s2 = 0.f;
#pragma unroll
    for (int j = 0; j < 16; ++j) {
      const int i = j * 64 + l;
      const float x = memb[n * 1024 + i] + bf2f(sAtt[n * 1024 + i]);
      xs[j] = x; s += x; s2 += x * x;
    }
#pragma unroll
    for (int o = 32; o; o >>= 1) { s += __shfl_xor(s, o); s2 += __shfl_xor(s2, o); }
    const float mean = s * (1.f / 1024.f);
    const float rstd = rsqrtf(s2 * (1.f / 1024.f) - mean * mean + 1e-5f);
    unsigned short* dst = m1 + ((size_t)b * 8 + n) * 1024;
#pragma unroll
    for (int j = 0; j < 16; ++j) {
      const int i = j * 64 + l;
      dst[i] = f2bf((xs[j] - mean) * rstd * g1[i] + b1[i]);
    }
  }
}

// ---------- LN2: m2 = LN(m1 + mlp) ----------
__global__ void __launch_bounds__(256)
ln2_kernel(const unsigned short* __restrict__ m1, const unsigned short* __restrict__ mlp,
           const float* __restrict__ g, const float* __restrict__ bb,
           unsigned short* __restrict__ m2)
{
  const int row = blockIdx.x, t = threadIdx.x;
  const ushort4 v1 = ((const ushort4*)(m1 + (size_t)row * 1024))[t];
  const ushort4 v2 = ((const ushort4*)(mlp + (size_t)row * 1024))[t];
  const float x0 = bf2f(v1.x) + bf2f(v2.x), x1 = bf2f(v1.y) + bf2f(v2.y),
              x2 = bf2f(v1.z) + bf2f(v2.z), x3 = bf2f(v1.w) + bf2f(v2.w);
  float s = x0 + x1 + x2 + x3;
  float s2 = x0 * x0 + x1 * x1 + x2 * x2 + x3 * x3;
#pragma unroll
  for (int o = 32; o; o >>= 1) { s += __shfl_xor(s, o); s2 += __shfl_xor(s2, o); }
  __shared__ float rs[4], rq[4];
  const int wv = t >> 6, l = t & 63;
  if (l == 0) { rs[wv] = s; rq[wv] = s2; }
  __syncthreads();
  s = rs[0] + rs[1] + rs[2] + rs[3];
  s2 = rq[0] + rq[1] + rq[2] + rq[3];
  const float mean = s * (1.f / 1024.f);
  const float rstd = rsqrtf(s2 * (1.f / 1024.f) - mean * mean + 1e-5f);
  const float4 gv = ((const float4*)g)[t];
  const float4 bv = ((const float4*)bb)[t];
  ushort4 ov;
  ov.x = f2bf((x0 - mean) * rstd * gv.x + bv.x);
  ov.y = f2bf((x1 - mean) * rstd * gv.y + bv.y);
  ov.z = f2bf((x2 - mean) * rstd * gv.z + bv.z);
  ov.w = f2bf((x3 - mean) * rstd * gv.w + bv.w);
  ((ushort4*)(m2 + (size_t)row * 1024))[t] = ov;
}

// ---------- final: next = sig_i * tanh(m2) + sig_f * memory; dual write ----------
__global__ void __launch_bounds__(256)
final_kernel(const unsigned short* __restrict__ sg,   // sigmoided gates [32768][2048] bf16
             const unsigned short* __restrict__ m2,   // [32768][1024] bf16
             const float* __restrict__ memF,          // fp32 memory
             float* __restrict__ out)
{
  const int e4 = blockIdx.x * 256 + threadIdx.x;      // float4/ushort4 index, 8388608 total
  const int row = e4 >> 8;
  const int c4 = e4 & 255;
  const ushort4 iv = ((const ushort4*)(sg + (size_t)row * 2048))[c4];
  const ushort4 fv = ((const ushort4*)(sg + (size_t)row * 2048 + 1024))[c4];
  const ushort4 mv = ((const ushort4*)m2)[e4];
  const float4 me = ((const float4*)memF)[e4];
  float4 r;
  r.x = bf2f(iv.x) * tanhf(bf2f(mv.x)) + bf2f(fv.x) * me.x;
  r.y = bf2f(iv.y) * tanhf(bf2f(mv.y)) + bf2f(fv.y) * me.y;
  r.z = bf2f(iv.z) * tanhf(bf2f(mv.z)) + bf2f(fv.z) * me.z;
  r.w = bf2f(iv.w) * tanhf(bf2f(mv.w)) + bf2f(fv.w) * me.w;
  ((float4*)out)[e4] = r;                 // output (B,8192)
  ((float4*)out)[8388608 + e4] = r;       // next_memory (B,8,1024) — same values
}

// ---------- launch ----------
extern "C" void kernel_launch(void* const* d_in, const int* in_sizes, int n_in,
                              void* d_out, int out_size, void* d_ws, size_t ws_size,
                              hipStream_t stream) {
  (void)in_sizes; (void)n_in; (void)out_size; (void)ws_size;
  const float* input_vec = (const float*)d_in[0];
  const float* memory    = (const float*)d_in[1];
  const float* qkv_w  = (const float*)d_in[2];
  const float* qkv_b  = (const float*)d_in[3];
  const float* qkvn_g = (const float*)d_in[4];
  const float* qkvn_b = (const float*)d_in[5];
  const float* mlp1_w = (const float*)d_in[6];
  const float* mlp1_b = (const float*)d_in[7];
  const float* mlp2_w = (const float*)d_in[8];
  const float* mlp2_b = (const float*)d_in[9];
  const float* n1_g = (const float*)d_in[10];
  const float* n1_b = (const float*)d_in[11];
  const float* n2_g = (const float*)d_in[12];
  const float* n2_b = (const float*)d_in[13];
  const float* inp_w = (const float*)d_in[14];
  const float* inp_b = (const float*)d_in[15];
  const float* ig_w  = (const float*)d_in[16];
  const float* ig_b  = (const float*)d_in[17];
  const float* mg_w  = (const float*)d_in[18];
  const float* mg_b  = (const float*)d_in[19];
  const float* forget_bias = (const float*)d_in[20];
  const float* input_bias  = (const float*)d_in[21];

  char* p = (char*)d_ws;
  auto carve = [&](size_t bytes) -> void* {
    void* r = (void*)p; p += (bytes + 255) & ~(size_t)255; return r;
  };
  unsigned short* mem_bf  = (unsigned short*)carve(67108864);   // memory bf16 [B*8][1024]
  unsigned short* iv_bf   = (unsigned short*)carve(8388608);    // input_vec bf16
  unsigned short* inp_bf  = (unsigned short*)carve(8388608);    // inp bf16 [B][1024]
  unsigned short* inp_wT  = (unsigned short*)carve(2097152);
  unsigned short* qkv_wT  = (unsigned short*)carve(6291456);
  unsigned short* mlp1_wT = (unsigned short*)carve(2097152);
  unsigned short* mlp2_wT = (unsigned short*)carve(2097152);
  unsigned short* ig_wT   = (unsigned short*)carve(4194304);
  unsigned short* mg_wT   = (unsigned short*)carve(4194304);
  char* big               = (char*)carve(226492416);            // qkv_pre region (reused)
  unsigned short* qkv_pre = (unsigned short*)big;               // [36864][3072] bf16
  unsigned short* gates   = (unsigned short*)big;               // later: [32768][2048] bf16
  unsigned short* mlp_buf = (unsigned short*)(big + 134217728); // later: [32768][1024] bf16
  unsigned short* m1      = (unsigned short*)carve(67108864);   // [32768][1024] bf16
  unsigned short* h_buf   = (unsigned short*)carve(67108864);   // relu hidden; later m2
  unsigned short* m2      = h_buf;                              // overlay (h dead after G4)
  unsigned short* ig_part = (unsigned short*)carve(16777216);   // [4096][2048] bf16

  const dim3 tb(32, 8);
  wtrans_kernel<<<dim3(32, 32), tb, 0, stream>>>(inp_w,  inp_wT,  1024, 1024);
  wtrans_kernel<<<dim3(96, 32), tb, 0, stream>>>(qkv_w,  qkv_wT,  1024, 3072);
  wtrans_kernel<<<dim3(32, 32), tb, 0, stream>>>(mlp1_w, mlp1_wT, 1024, 1024);
  wtrans_kernel<<<dim3(32, 32), tb, 0, stream>>>(mlp2_w, mlp2_wT, 1024, 1024);
  wtrans_kernel<<<dim3(64, 32), tb, 0, stream>>>(ig_w,   ig_wT,   1024, 2048);
  wtrans_kernel<<<dim3(64, 32), tb, 0, stream>>>(mg_w,   mg_wT,   1024, 2048);
  cvt_f32_bf16<<<2048, 256, 0, stream>>>(input_vec, iv_bf, 1048576);
  cvt_f32_bf16<<<2048, 256, 0, stream>>>(memory, mem_bf, 8388608);

  // inp = input_vec @ inp_w + inp_b           (4096x1024x1024, 256 blocks)
  gemm_bt<0, 0><<<256, 256, 0, stream>>>(iv_bf, nullptr, inp_wT, inp_b,
      nullptr, nullptr, nullptr, inp_bf, /*tilesN=*/8, 1024, 1024);
  // qkv_pre = concat(memory, inp) @ qkv_w + qkv_b   (36864x3072x1024, 6912 blocks)
  gemm_bt<1, 0><<<6912, 256, 0, stream>>>(mem_bf, inp_bf, qkv_wT, qkv_b,
      nullptr, nullptr, nullptr, qkv_pre, /*tilesN=*/24, 3072, 1024);
  // LN(qkv) -> attention -> +memory residual -> LN1 -> m1
  attn_fused<<<4096, 256, 0, stream>>>(qkv_pre, qkvn_g, qkvn_b, memory, n1_g, n1_b, m1);
  // h = relu(m1 @ mlp1_w + mlp1_b)            (32768x1024x1024, 2048 blocks)
  gemm_bt<0, 1><<<2048, 256, 0, stream>>>(m1, nullptr, mlp1_wT, mlp1_b,
      nullptr, nullptr, nullptr, h_buf, /*tilesN=*/8, 1024, 1024);
  // mlp = h @ mlp2_w + mlp2_b
  gemm_bt<0, 0><<<2048, 256, 0, stream>>>(h_buf, nullptr, mlp2_wT, mlp2_b,
      nullptr, nullptr, nullptr, mlp_buf, /*tilesN=*/8, 1024, 1024);
  // m2 = LN(m1 + mlp)    (writes over h_buf — h is dead now)
  ln2_kernel<<<32768, 256, 0, stream>>>(m1, mlp_buf, n2_g, n2_b, m2);
  // ig_part = inp @ ig_w + ig_b               (4096x2048x1024, 512 blocks)
  gemm_bt<0, 0><<<512, 256, 0, stream>>>(inp_bf, nullptr, ig_wT, ig_b,
      nullptr, nullptr, nullptr, ig_part, /*tilesN=*/16, 2048, 1024);
  // gates = sigmoid(memory @ mg_w + mg_b + ig_part + input/forget bias)  (4096 blocks)
  gemm_bt<0, 3><<<4096, 256, 0, stream>>>(mem_bf, nullptr, mg_wT, mg_b,
      ig_part, input_bias, forget_bias, gates, /*tilesN=*/16, 2048, 1024);
  // next_memory = i*tanh(m2) + f*memory ; write both output halves
  final_kernel<<<32768, 256, 0, stream>>>(gates, m2, memory, (float*)d_out);
}

// Round 4
// 1500.586 us; speedup vs baseline: 1.0977x; 1.0977x over previous
//
#include <hip/hip_runtime.h>
#include <stdint.h>

// ---------- types / helpers ----------
typedef __attribute__((ext_vector_type(8))) short s16x8;   // 8 bf16 (4 VGPR) MFMA operand
typedef __attribute__((ext_vector_type(4))) float f32x4;   // MFMA accumulator

__device__ __forceinline__ float bf2f(unsigned short u) {
  union { unsigned int i; float f; } x; x.i = ((unsigned int)u) << 16; return x.f;
}
__device__ __forceinline__ unsigned short f2bf(float f) {
  union { float f; unsigned int i; } x; x.f = f;
  return (unsigned short)((x.i + 0x7FFFu + ((x.i >> 16) & 1u)) >> 16);  // RNE
}
__device__ __forceinline__ void gload16(const unsigned short* g, unsigned short* l) {
  __builtin_amdgcn_global_load_lds((const __attribute__((address_space(1))) void*)g,
                                   (__attribute__((address_space(3))) void*)l, 16, 0, 0);
}

// ---------- weight transpose + f32->bf16:  w[K][N] -> wt[N][K] ----------
__global__ void wtrans_kernel(const float* __restrict__ w, unsigned short* __restrict__ wt,
                              int K, int N) {
  __shared__ float tile[32][33];
  const int n0 = blockIdx.x * 32, k0 = blockIdx.y * 32;
  const int tx = threadIdx.x, ty = threadIdx.y;            // 32 x 8
  for (int r = 0; r < 32; r += 8)
    tile[ty + r][tx] = w[(size_t)(k0 + ty + r) * N + n0 + tx];
  __syncthreads();
  for (int r = 0; r < 32; r += 8)
    wt[(size_t)(n0 + ty + r) * K + k0 + tx] = f2bf(tile[tx][ty + r]);
}

// ---------- elementwise f32 -> bf16 (vectorized) ----------
__global__ void cvt_f32_bf16(const float* __restrict__ src, unsigned short* __restrict__ dst, int n4) {
  int i = blockIdx.x * blockDim.x + threadIdx.x;
  const int stride = gridDim.x * blockDim.x;
  for (; i < n4; i += stride) {
    float4 v = ((const float4*)src)[i];
    ushort4 o; o.x = f2bf(v.x); o.y = f2bf(v.y); o.z = f2bf(v.z); o.w = f2bf(v.w);
    ((ushort4*)dst)[i] = o;
  }
}

// ============================================================================
// gemm3: deep-pipelined bf16 MFMA GEMM (BM=256, BN=128, BK=64, 512 threads)
//   - triple-buffered LDS (3 x 48KB), tile t+2 staged during tile t
//   - counted s_waitcnt vmcnt(6) once per K-tile (loads in flight across barriers)
//   - T2 XOR swizzle (kb ^= (row&7)<<4): inverse-swizzled global src + swizzled ds_read
//   - 2 phases per K-tile, 16-MFMA clusters wrapped in s_setprio (T5)
//   - T1 XCD-bijective block swizzle (grid % 8 == 0 for all our shapes)
// AMODE 0: A row-major [M][K].  AMODE 1: concat rows r -> b=r/9,n=r%9 (n<8: A[b*8+n], else A2[b])
// EPI 0: +bias   EPI 1: relu(+bias)   EPI 3: sigmoid(+bias + igp[row/8][col] + sel-bias)
// ============================================================================
template<int AMODE, int EPI>
__global__ void __launch_bounds__(512, 2)
gemm3(const unsigned short* __restrict__ A,
      const unsigned short* __restrict__ A2,
      const unsigned short* __restrict__ Bt,
      const float* __restrict__ bias,
      const unsigned short* __restrict__ igp,
      const float* __restrict__ sib,
      const float* __restrict__ sfb,
      unsigned short* __restrict__ C,
      int tilesN, int N, int K)
{
  // slot layout (ushort offsets): A at s*24576 (256x64), B at s*24576+16384 (128x64)
  __shared__ __align__(16) unsigned short lds[3 * 24576];   // 147456 B
  const int tid = threadIdx.x;
  const int w = tid >> 6, l = tid & 63;
  const int lr = l & 15, lg = l >> 4;

  // T1 swizzle
  const int nwg = gridDim.x;
  const int cpx = nwg >> 3;
  const int lid = blockIdx.x;
  const int wgid = (lid & 7) * cpx + (lid >> 3);
  const int bty = wgid / tilesN;
  const int btx = wgid - bty * tilesN;
  const int brow = bty << 8;            // 256-row M tile
  const int bcol = btx << 7;            // 128-col N tile
  const int wr = w >> 2, wc = w & 3;    // 2M x 4N waves; wave tile 128 x 32

  // ---- staging descriptors: 6 chunks of 8KB per K-tile (A:0-3, B:4-5) ----
  // linear LDS byte o = c*8192 + tid*16 -> row = o>>7, kb = o&127 (row stride 128B)
  // source element pre-swizzled: kb ^ ((row&7)<<4)  (involution; read applies same XOR)
  const unsigned short* gsrc[6];
  int ldst[6];                                   // ushort offset within slot (wave-uniform)
  {
    const int sub = tid >> 3;                    // 0..63 : row-within-chunk
    const int kbs = ((tid & 7) << 4) ^ ((sub & 7) << 4);   // swizzled byte-in-row
#pragma unroll
    for (int c = 0; c < 6; ++c) {
      if (c < 4) {
        const int gr = brow + c * 64 + sub;      // global A row
        const unsigned short* rp;
        if (AMODE == 0) {
          rp = A + (size_t)gr * K;
        } else {
          const int bb = gr / 9;
          const int nn = gr - bb * 9;
          rp = (nn < 8) ? (A + ((size_t)(bb * 8 + nn)) * K) : (A2 + (size_t)bb * K);
        }
        gsrc[c] = rp + (kbs >> 1);
        ldst[c] = c * 4096 + (w << 9);
      } else {
        const int gc = bcol + (c - 4) * 64 + sub; // global B col
        gsrc[c] = Bt + (size_t)gc * K + (kbs >> 1);
        ldst[c] = 16384 + (c - 4) * 4096 + (w << 9);
      }
    }
  }

  // ---- fragment ds_read offsets (loop-invariant; slot base added per tile) ----
  const int swr = (lr & 7) << 4;                 // read-side swizzle (row&7 == lr&7)
  int aoff[8][2], boff[2][2];
#pragma unroll
  for (int m = 0; m < 8; ++m)
#pragma unroll
    for (int kk = 0; kk < 2; ++kk) {
      const int row = wr * 128 + m * 16 + lr;
      aoff[m][kk] = row * 64 + ((((kk << 6) | (lg << 4)) ^ swr) >> 1);
    }
#pragma unroll
  for (int n = 0; n < 2; ++n)
#pragma unroll
    for (int kk = 0; kk < 2; ++kk) {
      const int col = wc * 32 + n * 16 + lr;
      boff[n][kk] = 16384 + col * 64 + ((((kk << 6) | (lg << 4)) ^ swr) >> 1);
    }

  f32x4 acc[8][2] = {};
  const int NT = K >> 6;                         // K-tiles of 64 (16 for K=1024)

  // ---- prologue: stage tiles 0,1 into slots 0,1; wait tile 0 ----
#pragma unroll
  for (int c = 0; c < 6; ++c) gload16(gsrc[c], lds + ldst[c]);
#pragma unroll
  for (int c = 0; c < 6; ++c) gload16(gsrc[c] + 64, lds + 24576 + ldst[c]);
  asm volatile("s_waitcnt vmcnt(6)" ::: "memory");
  __builtin_amdgcn_s_barrier();

  int s = 0;
  for (int t = 0; t < NT; ++t) {
    const int sBase  = s * 24576;
    const int s2Base = ((s >= 1) ? (s - 1) : (s + 2)) * 24576;   // (s+2)%3
    const bool pf = (t + 2 < NT);
    const int ktn = (t + 2) << 6;               // element offset of tile t+2

    // ================= phase A : B-frags + A-frags m0..3, MFMA quad 0 ==========
    if (pf) {
      gload16(gsrc[0] + ktn, lds + s2Base + ldst[0]);
      gload16(gsrc[1] + ktn, lds + s2Base + ldst[1]);
      gload16(gsrc[2] + ktn, lds + s2Base + ldst[2]);
    }
    s16x8 bfr[2][2], af[4][2];
#pragma unroll
    for (int n = 0; n < 2; ++n)
#pragma unroll
      for (int kk = 0; kk < 2; ++kk)
        bfr[n][kk] = *(const s16x8*)(lds + sBase + boff[n][kk]);
#pragma unroll
    for (int m = 0; m < 4; ++m)
#pragma unroll
      for (int kk = 0; kk < 2; ++kk)
        af[m][kk] = *(const s16x8*)(lds + sBase + aoff[m][kk]);
    asm volatile("s_barrier" ::: "memory");
    __builtin_amdgcn_s_setprio(1);
#pragma unroll
    for (int kk = 0; kk < 2; ++kk)
#pragma unroll
      for (int m = 0; m < 4; ++m)
#pragma unroll
        for (int n = 0; n < 2; ++n)
          acc[m][n] = __builtin_amdgcn_mfma_f32_16x16x32_bf16(af[m][kk], bfr[n][kk], acc[m][n], 0, 0, 0);
    __builtin_amdgcn_s_setprio(0);
    asm volatile("s_barrier" ::: "memory");

    // ================= phase B : A-frags m4..7, MFMA quad 1 ====================
    if (pf) {
      gload16(gsrc[3] + ktn, lds + s2Base + ldst[3]);
      gload16(gsrc[4] + ktn, lds + s2Base + ldst[4]);
      gload16(gsrc[5] + ktn, lds + s2Base + ldst[5]);
    }
    s16x8 ag[4][2];
#pragma unroll
    for (int m = 0; m < 4; ++m)
#pragma unroll
      for (int kk = 0; kk < 2; ++kk)
        ag[m][kk] = *(const s16x8*)(lds + sBase + aoff[m + 4][kk]);
    asm volatile("s_barrier" ::: "memory");
    __builtin_amdgcn_s_setprio(1);
#pragma unroll
    for (int kk = 0; kk < 2; ++kk)
#pragma unroll
      for (int m = 0; m < 4; ++m)
#pragma unroll
        for (int n = 0; n < 2; ++n)
          acc[m + 4][n] = __builtin_amdgcn_mfma_f32_16x16x32_bf16(ag[m][kk], bfr[n][kk], acc[m + 4][n], 0, 0, 0);
    __builtin_amdgcn_s_setprio(0);
    // trailing barrier of the K-tile: counted wait for tile t+1's staging
    if (pf)                 asm volatile("s_waitcnt vmcnt(6)\ns_barrier" ::: "memory");
    else if (t + 1 < NT)    asm volatile("s_waitcnt vmcnt(0)\ns_barrier" ::: "memory");
    else                    asm volatile("s_barrier" ::: "memory");
    s = (s == 2) ? 0 : s + 1;
  }

  // ---- epilogue ----
  float ib = 0.f, fb = 0.f;
  if constexpr (EPI == 3) { ib = sib[0]; fb = sfb[0]; }
  const int row0 = brow + wr * 128 + (lg << 2);    // C/D: col=lane&15, row=(lane>>4)*4+j
  const int col0 = bcol + wc * 32 + lr;
#pragma unroll
  for (int m = 0; m < 8; ++m) {
#pragma unroll
    for (int n = 0; n < 2; ++n) {
      const int col = col0 + n * 16;
      const float bv = bias[col];
#pragma unroll
      for (int j = 0; j < 4; ++j) {
        const int row = row0 + m * 16 + j;
        float x = acc[m][n][j] + bv;
        if constexpr (EPI == 1) x = fmaxf(x, 0.f);
        if constexpr (EPI == 3) {
          x += bf2f(igp[(size_t)(row >> 3) * 2048 + col]);
          x += (col < 1024) ? ib : fb;
          x = 1.f / (1.f + expf(-x));
        }
        C[(size_t)row * N + col] = f2bf(x);
      }
    }
  }
}

// ---------- verified 2-phase 128x128 GEMM (kept for the two small GEMMs) ----------
template<int AMODE, int EPI>
__global__ void __launch_bounds__(256)
gemm_bt(const unsigned short* __restrict__ A,
        const unsigned short* __restrict__ A2,
        const unsigned short* __restrict__ Bt,
        const float* __restrict__ bias,
        const unsigned short* __restrict__ igp,
        const float* __restrict__ sib,
        const float* __restrict__ sfb,
        unsigned short* __restrict__ C,
        int tilesN, int N, int K)
{
  __shared__ __align__(16) unsigned short As[128 * 32];
  __shared__ __align__(16) unsigned short Bs[128 * 32];
  const int t = threadIdx.x;
  const int w = t >> 6, l = t & 63;

  const int nwg = gridDim.x;
  const int cpx = nwg >> 3;
  const int lid = blockIdx.x;
  const int wgid = (lid & 7) * cpx + (lid >> 3);
  const int bty = wgid / tilesN;
  const int btx = wgid - bty * tilesN;
  const int brow = bty << 7, bcol = btx << 7;
  const int wr = w >> 1, wc = w & 1;

  const unsigned short* ap[2];
  const unsigned short* bp[2];
  unsigned short* al[2];
  unsigned short* bl[2];
#pragma unroll
  for (int p0 = 0; p0 < 2; ++p0) {
    const int byteoff = ((p0 * 4 + w) << 10) + (l << 4);
    const int row = byteoff >> 6;
    const int ce  = (byteoff & 63) >> 1;
    const int ar  = brow + row;
    if (AMODE == 0) {
      ap[p0] = A + (size_t)ar * K + ce;
    } else {
      const int bb = ar / 9;
      const int nn = ar - bb * 9;
      ap[p0] = (nn < 8 ? (A + ((size_t)(bb * 8 + nn)) * K) : (A2 + (size_t)bb * K)) + ce;
    }
    bp[p0] = Bt + (size_t)(bcol + row) * K + ce;
    al[p0] = As + ((p0 * 4 + w) << 9);
    bl[p0] = Bs + ((p0 * 4 + w) << 9);
  }

  f32x4 acc[4][4] = {};
  const int kiters = K >> 5;
  for (int kt = 0; kt < kiters; ++kt) {
#pragma unroll
    for (int p0 = 0; p0 < 2; ++p0) {
      gload16(ap[p0], al[p0]);
      gload16(bp[p0], bl[p0]);
      ap[p0] += 32; bp[p0] += 32;
    }
    __syncthreads();
    const int lr = l & 15, lk = (l >> 4) << 3;
    s16x8 af[4], bfr[4];
#pragma unroll
    for (int m = 0; m < 4; ++m)
      af[m] = *(const s16x8*)(As + ((wr * 64 + m * 16 + lr) << 5) + lk);
#pragma unroll
    for (int n = 0; n < 4; ++n)
      bfr[n] = *(const s16x8*)(Bs + ((wc * 64 + n * 16 + lr) << 5) + lk);
#pragma unroll
    for (int m = 0; m < 4; ++m)
#pragma unroll
      for (int n = 0; n < 4; ++n)
        acc[m][n] = __builtin_amdgcn_mfma_f32_16x16x32_bf16(af[m], bfr[n], acc[m][n], 0, 0, 0);
    __syncthreads();
  }

  float ib = 0.f, fb = 0.f;
  if constexpr (EPI == 3) { ib = sib[0]; fb = sfb[0]; }
  const int row0 = brow + wr * 64 + ((l >> 4) << 2);
  const int col0 = bcol + wc * 64 + (l & 15);
#pragma unroll
  for (int m = 0; m < 4; ++m) {
#pragma unroll
    for (int n = 0; n < 4; ++n) {
      const int col = col0 + n * 16;
      const float bv = bias[col];
#pragma unroll
      for (int j = 0; j < 4; ++j) {
        const int row = row0 + m * 16 + j;
        float x = acc[m][n][j] + bv;
        if constexpr (EPI == 1) x = fmaxf(x, 0.f);
        if constexpr (EPI == 3) {
          x += bf2f(igp[(size_t)(row >> 3) * 2048 + col]);
          x += (col < 1024) ? ib : fb;
          x = 1.f / (1.f + expf(-x));
        }
        C[(size_t)row * N + col] = f2bf(x);
      }
    }
  }
}

// ---------- fused: qkv-LN -> attention -> residual -> LN1 ----------
#define QROW 3080
__global__ void __launch_bounds__(256)
attn_fused(const unsigned short* __restrict__ qkv,
           const float* __restrict__ g3, const float* __restrict__ b3,
           const float* __restrict__ memF,
           const float* __restrict__ g1, const float* __restrict__ b1,
           unsigned short* __restrict__ m1)
{
  __shared__ __align__(16) unsigned short sQ[9 * QROW];
  __shared__ float sS[16][8][12];
  __shared__ __align__(16) unsigned short sAtt[8 * 1024];
  const int b = blockIdx.x;
  const int t = threadIdx.x;
  const int wv = t >> 6, l = t & 63;

  const unsigned short* src = qkv + (size_t)b * (9 * 3072);
  for (int i = t; i < 3456; i += 256) {
    const int r = i / 384;
    const int c = i - r * 384;
    ((uint4*)(sQ + r * QROW))[c] = ((const uint4*)src)[i];
  }
  __syncthreads();

  for (int r = wv; r < 9; r += 4) {
    float s = 0.f, s2 = 0.f;
    for (int i = l; i < 3072; i += 64) {
      const float x = bf2f(sQ[r * QROW + i]); s += x; s2 += x * x;
    }
#pragma unroll
    for (int o = 32; o; o >>= 1) { s += __shfl_xor(s, o); s2 += __shfl_xor(s2, o); }
    const float mean = s * (1.f / 3072.f);
    const float rstd = rsqrtf(s2 * (1.f / 3072.f) - mean * mean + 1e-5f);
    for (int i = l; i < 3072; i += 64) {
      const float x = bf2f(sQ[r * QROW + i]);
      sQ[r * QROW + i] = f2bf((x - mean) * rstd * g3[i] + b3[i]);
    }
  }
  __syncthreads();

  for (int idx = t; idx < 1152; idx += 256) {
    const int h = idx / 72;
    const int rem = idx - h * 72;
    const int n = rem / 9;
    const int m = rem - n * 9;
    const ushort4* q4 = (const ushort4*)(sQ + n * QROW + h * 192);
    const ushort4* k4 = (const ushort4*)(sQ + m * QROW + h * 192 + 64);
    float acc = 0.f;
#pragma unroll
    for (int d = 0; d < 16; ++d) {
      const ushort4 qa = q4[d], ka = k4[d];
      acc += bf2f(qa.x) * bf2f(ka.x) + bf2f(qa.y) * bf2f(ka.y)
           + bf2f(qa.z) * bf2f(ka.z) + bf2f(qa.w) * bf2f(ka.w);
    }
    sS[h][n][m] = acc * 0.125f;
  }
  __syncthreads();

  if (t < 128) {
    const int h = t >> 3, n = t & 7;
    float mx = -1e30f;
#pragma unroll
    for (int m = 0; m < 9; ++m) mx = fmaxf(mx, sS[h][n][m]);
    float p[9]; float sum = 0.f;
#pragma unroll
    for (int m = 0; m < 9; ++m) { p[m] = expf(sS[h][n][m] - mx); sum += p[m]; }
    const float inv = 1.f / sum;
#pragma unroll
    for (int m = 0; m < 9; ++m) sS[h][n][m] = p[m] * inv;
  }
  __syncthreads();

  for (int o4 = t; o4 < 2048; o4 += 256) {
    const int n = o4 >> 8;
    const int rem = o4 & 255;
    const int h = rem >> 4;
    const int d4 = rem & 15;
    float a0 = 0, a1 = 0, a2 = 0, a3 = 0;
#pragma unroll
    for (int m = 0; m < 9; ++m) {
      const float pm = sS[h][n][m];
      const ushort4 vv = *(const ushort4*)(sQ + m * QROW + h * 192 + 128 + d4 * 4);
      a0 += pm * bf2f(vv.x); a1 += pm * bf2f(vv.y); a2 += pm * bf2f(vv.z); a3 += pm * bf2f(vv.w);
    }
    ushort4 ov; ov.x = f2bf(a0); ov.y = f2bf(a1); ov.z = f2bf(a2); ov.w = f2bf(a3);
    ((ushort4*)sAtt)[o4] = ov;
  }
  __syncthreads();

  const float* memb = memF + (size_t)b * 8192;
  for (int n = wv; n < 8; n += 4) {
    float xs[16]; float s = 0.f, s2 = 0.f;
#pragma unroll
    for (int j = 0; j < 16; ++j) {
      const int i = j * 64 + l;
      const float x = memb[n * 1024 + i] + bf2f(sAtt[n * 1024 + i]);
      xs[j] = x; s += x; s2 += x * x;
    }
#pragma unroll
    for (int o = 32; o; o >>= 1) { s += __shfl_xor(s, o); s2 += __shfl_xor(s2, o); }
    const float mean = s * (1.f / 1024.f);
    const float rstd = rsqrtf(s2 * (1.f / 1024.f) - mean * mean + 1e-5f);
    unsigned short* dst = m1 + ((size_t)b * 8 + n) * 1024;
#pragma unroll
    for (int j = 0; j < 16; ++j) {
      const int i = j * 64 + l;
      dst[i] = f2bf((xs[j] - mean) * rstd * g1[i] + b1[i]);
    }
  }
}

// ---------- LN2: m2 = LN(m1 + mlp) ----------
__global__ void __launch_bounds__(256)
ln2_kernel(const unsigned short* __restrict__ m1, const unsigned short* __restrict__ mlp,
           const float* __restrict__ g, const float* __restrict__ bb,
           unsigned short* __restrict__ m2)
{
  const int row = blockIdx.x, t = threadIdx.x;
  const ushort4 v1 = ((const ushort4*)(m1 + (size_t)row * 1024))[t];
  const ushort4 v2 = ((const ushort4*)(mlp + (size_t)row * 1024))[t];
  const float x0 = bf2f(v1.x) + bf2f(v2.x), x1 = bf2f(v1.y) + bf2f(v2.y),
              x2 = bf2f(v1.z) + bf2f(v2.z), x3 = bf2f(v1.w) + bf2f(v2.w);
  float s = x0 + x1 + x2 + x3;
  float s2 = x0 * x0 + x1 * x1 + x2 * x2 + x3 * x3;
#pragma unroll
  for (int o = 32; o; o >>= 1) { s += __shfl_xor(s, o); s2 += __shfl_xor(s2, o); }
  __shared__ float rs[4], rq[4];
  const int wv = t >> 6, l = t & 63;
  if (l == 0) { rs[wv] = s; rq[wv] = s2; }
  __syncthreads();
  s = rs[0] + rs[1] + rs[2] + rs[3];
  s2 = rq[0] + rq[1] + rq[2] + rq[3];
  const float mean = s * (1.f / 1024.f);
  const float rstd = rsqrtf(s2 * (1.f / 1024.f) - mean * mean + 1e-5f);
  const float4 gv = ((const float4*)g)[t];
  const float4 bv = ((const float4*)bb)[t];
  ushort4 ov;
  ov.x = f2bf((x0 - mean) * rstd * gv.x + bv.x);
  ov.y = f2bf((x1 - mean) * rstd * gv.y + bv.y);
  ov.z = f2bf((x2 - mean) * rstd * gv.z + bv.z);
  ov.w = f2bf((x3 - mean) * rstd * gv.w + bv.w);
  ((ushort4*)(m2 + (size_t)row * 1024))[t] = ov;
}

// ---------- final: next = sig_i * tanh(m2) + sig_f * memory; dual write ----------
__global__ void __launch_bounds__(256)
final_kernel(const unsigned short* __restrict__ sg,
             const unsigned short* __restrict__ m2,
             const float* __restrict__ memF,
             float* __restrict__ out)
{
  const int e4 = blockIdx.x * 256 + threadIdx.x;
  const int row = e4 >> 8;
  const int c4 = e4 & 255;
  const ushort4 iv = ((const ushort4*)(sg + (size_t)row * 2048))[c4];
  const ushort4 fv = ((const ushort4*)(sg + (size_t)row * 2048 + 1024))[c4];
  const ushort4 mv = ((const ushort4*)m2)[e4];
  const float4 me = ((const float4*)memF)[e4];
  float4 r;
  r.x = bf2f(iv.x) * tanhf(bf2f(mv.x)) + bf2f(fv.x) * me.x;
  r.y = bf2f(iv.y) * tanhf(bf2f(mv.y)) + bf2f(fv.y) * me.y;
  r.z = bf2f(iv.z) * tanhf(bf2f(mv.z)) + bf2f(fv.z) * me.z;
  r.w = bf2f(iv.w) * tanhf(bf2f(mv.w)) + bf2f(fv.w) * me.w;
  ((float4*)out)[e4] = r;
  ((float4*)out)[8388608 + e4] = r;
}

// ---------- launch ----------
extern "C" void kernel_launch(void* const* d_in, const int* in_sizes, int n_in,
                              void* d_out, int out_size, void* d_ws, size_t ws_size,
                              hipStream_t stream) {
  (void)in_sizes; (void)n_in; (void)out_size; (void)ws_size;
  const float* input_vec = (const float*)d_in[0];
  const float* memory    = (const float*)d_in[1];
  const float* qkv_w  = (const float*)d_in[2];
  const float* qkv_b  = (const float*)d_in[3];
  const float* qkvn_g = (const float*)d_in[4];
  const float* qkvn_b = (const float*)d_in[5];
  const float* mlp1_w = (const float*)d_in[6];
  const float* mlp1_b = (const float*)d_in[7];
  const float* mlp2_w = (const float*)d_in[8];
  const float* mlp2_b = (const float*)d_in[9];
  const float* n1_g = (const float*)d_in[10];
  const float* n1_b = (const float*)d_in[11];
  const float* n2_g = (const float*)d_in[12];
  const float* n2_b = (const float*)d_in[13];
  const float* inp_w = (const float*)d_in[14];
  const float* inp_b = (const float*)d_in[15];
  const float* ig_w  = (const float*)d_in[16];
  const float* ig_b  = (const float*)d_in[17];
  const float* mg_w  = (const float*)d_in[18];
  const float* mg_b  = (const float*)d_in[19];
  const float* forget_bias = (const float*)d_in[20];
  const float* input_bias  = (const float*)d_in[21];

  char* p = (char*)d_ws;
  auto carve = [&](size_t bytes) -> void* {
    void* r = (void*)p; p += (bytes + 255) & ~(size_t)255; return r;
  };
  unsigned short* mem_bf  = (unsigned short*)carve(67108864);
  unsigned short* iv_bf   = (unsigned short*)carve(8388608);
  unsigned short* inp_bf  = (unsigned short*)carve(8388608);
  unsigned short* inp_wT  = (unsigned short*)carve(2097152);
  unsigned short* qkv_wT  = (unsigned short*)carve(6291456);
  unsigned short* mlp1_wT = (unsigned short*)carve(2097152);
  unsigned short* mlp2_wT = (unsigned short*)carve(2097152);
  unsigned short* ig_wT   = (unsigned short*)carve(4194304);
  unsigned short* mg_wT   = (unsigned short*)carve(4194304);
  char* big               = (char*)carve(226492416);
  unsigned short* qkv_pre = (unsigned short*)big;
  unsigned short* gates   = (unsigned short*)big;
  unsigned short* mlp_buf = (unsigned short*)(big + 134217728);
  unsigned short* m1      = (unsigned short*)carve(67108864);
  unsigned short* h_buf   = (unsigned short*)carve(67108864);
  unsigned short* m2      = h_buf;
  unsigned short* ig_part = (unsigned short*)carve(16777216);

  const dim3 tb(32, 8);
  wtrans_kernel<<<dim3(32, 32), tb, 0, stream>>>(inp_w,  inp_wT,  1024, 1024);
  wtrans_kernel<<<dim3(96, 32), tb, 0, stream>>>(qkv_w,  qkv_wT,  1024, 3072);
  wtrans_kernel<<<dim3(32, 32), tb, 0, stream>>>(mlp1_w, mlp1_wT, 1024, 1024);
  wtrans_kernel<<<dim3(32, 32), tb, 0, stream>>>(mlp2_w, mlp2_wT, 1024, 1024);
  wtrans_kernel<<<dim3(64, 32), tb, 0, stream>>>(ig_w,   ig_wT,   1024, 2048);
  wtrans_kernel<<<dim3(64, 32), tb, 0, stream>>>(mg_w,   mg_wT,   1024, 2048);
  cvt_f32_bf16<<<2048, 256, 0, stream>>>(input_vec, iv_bf, 1048576);
  cvt_f32_bf16<<<2048, 256, 0, stream>>>(memory, mem_bf, 8388608);

  // inp = input_vec @ inp_w + inp_b           (4096x1024x1024, 2-phase 128^2)
  gemm_bt<0, 0><<<256, 256, 0, stream>>>(iv_bf, nullptr, inp_wT, inp_b,
      nullptr, nullptr, nullptr, inp_bf, /*tilesN=*/8, 1024, 1024);
  // qkv_pre = concat(memory, inp) @ qkv_w + qkv_b   (36864x3072x1024, gemm3: 144x24)
  gemm3<1, 0><<<3456, 512, 0, stream>>>(mem_bf, inp_bf, qkv_wT, qkv_b,
      nullptr, nullptr, nullptr, qkv_pre, /*tilesN=*/24, 3072, 1024);
  // LN(qkv) -> attention -> +memory residual -> LN1 -> m1
  attn_fused<<<4096, 256, 0, stream>>>(qkv_pre, qkvn_g, qkvn_b, memory, n1_g, n1_b, m1);
  // h = relu(m1 @ mlp1_w + mlp1_b)            (32768x1024x1024, gemm3: 128x8)
  gemm3<0, 1><<<1024, 512, 0, stream>>>(m1, nullptr, mlp1_wT, mlp1_b,
      nullptr, nullptr, nullptr, h_buf, /*tilesN=*/8, 1024, 1024);
  // mlp = h @ mlp2_w + mlp2_b
  gemm3<0, 0><<<1024, 512, 0, stream>>>(h_buf, nullptr, mlp2_wT, mlp2_b,
      nullptr, nullptr, nullptr, mlp_buf, /*tilesN=*/8, 1024, 1024);
  // m2 = LN(m1 + mlp)
  ln2_kernel<<<32768, 256, 0, stream>>>(m1, mlp_buf, n2_g, n2_b, m2);
  // ig_part = inp @ ig_w + ig_b               (4096x2048x1024, 2-phase 128^2)
  gemm_bt<0, 0><<<512, 256, 0, stream>>>(inp_bf, nullptr, ig_wT, ig_b,
      nullptr, nullptr, nullptr, ig_part, /*tilesN=*/16, 2048, 1024);
  // gates = sigmoid(memory @ mg_w + mg_b + ig_part + sel bias)  (gemm3: 128x16)
  gemm3<0, 3><<<2048, 512, 0, stream>>>(mem_bf, nullptr, mg_wT, mg_b,
      ig_part, input_bias, forget_bias, gates, /*tilesN=*/16, 2048, 1024);
  // next_memory = i*tanh(m2) + f*memory ; dual write
  final_kernel<<<32768, 256, 0, stream>>>(gates, m2, memory, (float*)d_out);
}

// Round 5
// 1438.339 us; speedup vs baseline: 1.1452x; 1.0433x over previous
//
#include <hip/hip_runtime.h>
#include <stdint.h>

// ---------- types / helpers ----------
typedef __attribute__((ext_vector_type(8))) short s16x8;   // 8 bf16 (4 VGPR) MFMA operand
typedef __attribute__((ext_vector_type(4))) float f32x4;   // MFMA accumulator

__device__ __forceinline__ float bf2f(unsigned short u) {
  union { unsigned int i; float f; } x; x.i = ((unsigned int)u) << 16; return x.f;
}
__device__ __forceinline__ unsigned short f2bf(float f) {
  union { float f; unsigned int i; } x; x.f = f;
  return (unsigned short)((x.i + 0x7FFFu + ((x.i >> 16) & 1u)) >> 16);  // RNE
}
__device__ __forceinline__ void gload16(const unsigned short* g, unsigned short* l) {
  __builtin_amdgcn_global_load_lds((const __attribute__((address_space(1))) void*)g,
                                   (__attribute__((address_space(3))) void*)l, 16, 0, 0);
}

// ---------- weight transpose + f32->bf16:  w[K][N] -> wt[N][K] ----------
__global__ void wtrans_kernel(const float* __restrict__ w, unsigned short* __restrict__ wt,
                              int K, int N) {
  __shared__ float tile[32][33];
  const int n0 = blockIdx.x * 32, k0 = blockIdx.y * 32;
  const int tx = threadIdx.x, ty = threadIdx.y;            // 32 x 8
  for (int r = 0; r < 32; r += 8)
    tile[ty + r][tx] = w[(size_t)(k0 + ty + r) * N + n0 + tx];
  __syncthreads();
  for (int r = 0; r < 32; r += 8)
    wt[(size_t)(n0 + ty + r) * K + k0 + tx] = f2bf(tile[tx][ty + r]);
}

// ---------- elementwise f32 -> bf16 (vectorized) ----------
__global__ void cvt_f32_bf16(const float* __restrict__ src, unsigned short* __restrict__ dst, int n4) {
  int i = blockIdx.x * blockDim.x + threadIdx.x;
  const int stride = gridDim.x * blockDim.x;
  for (; i < n4; i += stride) {
    float4 v = ((const float4*)src)[i];
    ushort4 o; o.x = f2bf(v.x); o.y = f2bf(v.y); o.z = f2bf(v.z); o.w = f2bf(v.w);
    ((ushort4*)dst)[i] = o;
  }
}

// ============================================================================
// gemm4: 256x256 tile, BK=64, 512 threads (8 waves, 2M x 4N), wave tile 128x64
//   - double-buffered LDS (2 x 64KB): slot = A[256][64] + B[256][64]
//   - 4 quadrant-phases per K-tile; all ds_reads in phases 1-2
//   - staging: 4 units/K-tile (A-h0,A-h1,B-h0,B-h1; 2 gload_lds each):
//       ph1,ph2 -> other slot (tile t+1: B-h0,B-h1)
//       ph3,ph4 -> current slot (tile t+2: A-h0,A-h1) [safe: reads drained at ph2 barrier]
//   - counted trailing s_waitcnt vmcnt(4) per K-tile (never 0 in steady state)
//   - T2 XOR swizzle byte^=(row&7)<<4 (pre-swizzled global src + swizzled ds_read)
//   - T5 setprio around MFMA clusters; T1 XCD-bijective block swizzle
// AMODE 0: A row-major [M][K].  AMODE 1: concat rows r -> b=r/9,n=r%9 (n<8: A[b*8+n], else A2[b])
// EPI 0: +bias   EPI 1: relu(+bias)   EPI 3: sigmoid(+bias + igp[row/8][col] + sel-bias)
// Requires K >= 128 (NT >= 2). K=1024 here.
// ============================================================================
template<int AMODE, int EPI>
__global__ void __launch_bounds__(512, 2)
gemm4(const unsigned short* __restrict__ A,
      const unsigned short* __restrict__ A2,
      const unsigned short* __restrict__ Bt,
      const float* __restrict__ bias,
      const unsigned short* __restrict__ igp,
      const float* __restrict__ sib,
      const float* __restrict__ sfb,
      unsigned short* __restrict__ C,
      int tilesN, int N, int K)
{
  __shared__ __align__(16) unsigned short lds[2 * 32768];   // 131072 B
  const int tid = threadIdx.x;
  const int w = tid >> 6, l = tid & 63;
  const int lr = l & 15, lg = l >> 4;

  // T1 swizzle
  const int nwg = gridDim.x;
  const int cpx = nwg >> 3;
  const int lid = blockIdx.x;
  const int wgid = (lid & 7) * cpx + (lid >> 3);
  const int bty = wgid / tilesN;
  const int btx = wgid - bty * tilesN;
  const int brow = bty << 8;            // 256-row M tile
  const int bcol = btx << 8;            // 256-col N tile
  const int wr = w >> 2, wc = w & 3;    // 2M x 4N waves; wave tile 128 x 64

  // ---- staging: thread covers (row = i*64 + sub, 16B at swizzled kb) ----
  const int sub = tid >> 3;                              // 0..63
  const int kbs = ((tid & 7) << 4) ^ ((sub & 7) << 4);   // swizzled byte-in-row
  const size_t kstep64 = (size_t)64 * K;                 // +64 rows (dense A / B)

  const unsigned short* aP[2];     // A-half h, i=0 rows
  const unsigned short* aQ[2];     // A-half h, i=1 rows (AMODE 1 only)
  const unsigned short* bP[2];     // B-half h, i=0
#pragma unroll
  for (int h = 0; h < 2; ++h) {
    if (AMODE == 0) {
      aP[h] = A + (size_t)(brow + h * 128 + sub) * K + (kbs >> 1);
      aQ[h] = nullptr;
    } else {
#pragma unroll
      for (int i = 0; i < 2; ++i) {
        const int gr = brow + h * 128 + i * 64 + sub;
        const int bb = gr / 9;
        const int nn = gr - bb * 9;
        const unsigned short* rp =
            (nn < 8) ? (A + ((size_t)(bb * 8 + nn)) * K) : (A2 + (size_t)bb * K);
        if (i == 0) aP[h] = rp + (kbs >> 1); else aQ[h] = rp + (kbs >> 1);
      }
    }
    bP[h] = Bt + (size_t)(bcol + h * 128 + sub) * K + (kbs >> 1);
  }
  const int ldb = w << 9;   // wave-uniform ushort offset within a 4096-ushort chunk

  auto stage_a = [&](int h, int slotB, int kofs) {
    const unsigned short* s1 = (AMODE == 0) ? (aP[h] + kstep64 + kofs) : (aQ[h] + kofs);
    gload16(aP[h] + kofs, lds + slotB + h * 8192 + ldb);
    gload16(s1,           lds + slotB + h * 8192 + 4096 + ldb);
  };
  auto stage_b = [&](int h, int slotB, int kofs) {
    gload16(bP[h] + kofs,           lds + slotB + 16384 + h * 8192 + ldb);
    gload16(bP[h] + kstep64 + kofs, lds + slotB + 16384 + h * 8192 + 4096 + ldb);
  };

  // ---- fragment read constants ----
  const int swr = (lr & 7) << 4;
  const int kpart0 = (((lg << 4)) ^ swr) >> 1;          // kk=0, ushort units
  const int kpart1 = ((64 | (lg << 4)) ^ swr) >> 1;     // kk=1

  f32x4 acc[8][4] = {};   // [qm*4+m][qn*2+n]
  const int NT = K >> 6;

  // ---- prologue: tile0 all units -> slot0; tile1 A-h0,A-h1 -> slot1 ----
  stage_a(0, 0, 0); stage_a(1, 0, 0); stage_b(0, 0, 0); stage_b(1, 0, 0);
  stage_a(0, 32768, 64); stage_a(1, 32768, 64);
  asm volatile("s_waitcnt vmcnt(4)" ::: "memory");
  __builtin_amdgcn_s_barrier();

#define MFMA_Q(AF, BF, RB, CB)                                                  \
  _Pragma("unroll") for (int kk = 0; kk < 2; ++kk)                              \
  _Pragma("unroll") for (int m = 0; m < 4; ++m)                                 \
  _Pragma("unroll") for (int n = 0; n < 2; ++n)                                 \
    acc[(RB) + m][(CB) + n] = __builtin_amdgcn_mfma_f32_16x16x32_bf16(          \
        AF[m][kk], BF[n][kk], acc[(RB) + m][(CB) + n], 0, 0, 0);

  int cur = 0;
  for (int t = 0; t < NT; ++t) {
    const int curB = cur << 15;          // *32768
    const int nxtB = curB ^ 32768;
    const unsigned short* As = lds + curB;
    const unsigned short* Bs = As + 16384;
    const int k1 = (t + 1) << 6, k2 = (t + 2) << 6;
    const bool p1 = (t + 1 < NT), p2 = (t + 2 < NT);

    // ---- phase 1: quadrant (0,0); stage B-h0(t+1) -> nxt ----
    if (p1) stage_b(0, nxtB, k1);
    s16x8 a0[4][2], b0[2][2];
#pragma unroll
    for (int m = 0; m < 4; ++m) {
      const int ro = (wr * 128 + m * 16 + lr) * 64;
      a0[m][0] = *(const s16x8*)(As + ro + kpart0);
      a0[m][1] = *(const s16x8*)(As + ro + kpart1);
    }
#pragma unroll
    for (int n = 0; n < 2; ++n) {
      const int co = (wc * 64 + n * 16 + lr) * 64;
      b0[n][0] = *(const s16x8*)(Bs + co + kpart0);
      b0[n][1] = *(const s16x8*)(Bs + co + kpart1);
    }
    asm volatile("s_barrier" ::: "memory");
    __builtin_amdgcn_s_setprio(1);
    MFMA_Q(a0, b0, 0, 0)
    __builtin_amdgcn_s_setprio(0);
    asm volatile("s_barrier" ::: "memory");

    // ---- phase 2: quadrant (0,1); stage B-h1(t+1) -> nxt ----
    if (p1) stage_b(1, nxtB, k1);
    s16x8 a1[4][2], b1[2][2];
#pragma unroll
    for (int m = 0; m < 4; ++m) {
      const int ro = (wr * 128 + 64 + m * 16 + lr) * 64;
      a1[m][0] = *(const s16x8*)(As + ro + kpart0);
      a1[m][1] = *(const s16x8*)(As + ro + kpart1);
    }
#pragma unroll
    for (int n = 0; n < 2; ++n) {
      const int co = (wc * 64 + 32 + n * 16 + lr) * 64;
      b1[n][0] = *(const s16x8*)(Bs + co + kpart0);
      b1[n][1] = *(const s16x8*)(Bs + co + kpart1);
    }
    asm volatile("s_barrier" ::: "memory");
    __builtin_amdgcn_s_setprio(1);
    MFMA_Q(a0, b1, 0, 2)
    __builtin_amdgcn_s_setprio(0);
    asm volatile("s_barrier" ::: "memory");   // all cur-slot reads drained by every wave

    // ---- phase 3: quadrant (1,0); stage A-h0(t+2) -> cur (now safe) ----
    if (p2) stage_a(0, curB, k2);
    __builtin_amdgcn_s_setprio(1);
    MFMA_Q(a1, b0, 4, 0)
    __builtin_amdgcn_s_setprio(0);

    // ---- phase 4: quadrant (1,1); stage A-h1(t+2) -> cur ----
    if (p2) stage_a(1, curB, k2);
    __builtin_amdgcn_s_setprio(1);
    MFMA_Q(a1, b1, 4, 2)
    __builtin_amdgcn_s_setprio(0);
    if (p2)      asm volatile("s_waitcnt vmcnt(4)\ns_barrier" ::: "memory");
    else if (p1) asm volatile("s_waitcnt vmcnt(0)\ns_barrier" ::: "memory");
    else         asm volatile("s_barrier" ::: "memory");
    cur ^= 1;
  }
#undef MFMA_Q

  // ---- epilogue ----
  float ib = 0.f, fb = 0.f;
  if constexpr (EPI == 3) { ib = sib[0]; fb = sfb[0]; }
  const int row0 = brow + wr * 128 + (lg << 2);    // C/D: col=lane&15, row=(lane>>4)*4+j
  const int col0 = bcol + wc * 64 + lr;
#pragma unroll
  for (int i = 0; i < 8; ++i) {
    const int qm = i >> 2, m = i & 3;
#pragma unroll
    for (int jq = 0; jq < 4; ++jq) {
      const int qn = jq >> 1, n = jq & 1;
      const int col = col0 + qn * 32 + n * 16;
      const float bv = bias[col];
#pragma unroll
      for (int j = 0; j < 4; ++j) {
        const int row = row0 + qm * 64 + m * 16 + j;
        float x = acc[i][jq][j] + bv;
        if constexpr (EPI == 1) x = fmaxf(x, 0.f);
        if constexpr (EPI == 3) {
          x += bf2f(igp[(size_t)(row >> 3) * 2048 + col]);
          x += (col < 1024) ? ib : fb;
          x = 1.f / (1.f + expf(-x));
        }
        C[(size_t)row * N + col] = f2bf(x);
      }
    }
  }
}

// ---------- verified 2-phase 128x128 GEMM (small GEMMs: inp, ig) ----------
template<int AMODE, int EPI>
__global__ void __launch_bounds__(256)
gemm_bt(const unsigned short* __restrict__ A,
        const unsigned short* __restrict__ A2,
        const unsigned short* __restrict__ Bt,
        const float* __restrict__ bias,
        const unsigned short* __restrict__ igp,
        const float* __restrict__ sib,
        const float* __restrict__ sfb,
        unsigned short* __restrict__ C,
        int tilesN, int N, int K)
{
  __shared__ __align__(16) unsigned short As[128 * 32];
  __shared__ __align__(16) unsigned short Bs[128 * 32];
  const int t = threadIdx.x;
  const int w = t >> 6, l = t & 63;

  const int nwg = gridDim.x;
  const int cpx = nwg >> 3;
  const int lid = blockIdx.x;
  const int wgid = (lid & 7) * cpx + (lid >> 3);
  const int bty = wgid / tilesN;
  const int btx = wgid - bty * tilesN;
  const int brow = bty << 7, bcol = btx << 7;
  const int wr = w >> 1, wc = w & 1;

  const unsigned short* ap[2];
  const unsigned short* bp[2];
  unsigned short* al[2];
  unsigned short* bl[2];
#pragma unroll
  for (int p0 = 0; p0 < 2; ++p0) {
    const int byteoff = ((p0 * 4 + w) << 10) + (l << 4);
    const int row = byteoff >> 6;
    const int ce  = (byteoff & 63) >> 1;
    const int ar  = brow + row;
    if (AMODE == 0) {
      ap[p0] = A + (size_t)ar * K + ce;
    } else {
      const int bb = ar / 9;
      const int nn = ar - bb * 9;
      ap[p0] = (nn < 8 ? (A + ((size_t)(bb * 8 + nn)) * K) : (A2 + (size_t)bb * K)) + ce;
    }
    bp[p0] = Bt + (size_t)(bcol + row) * K + ce;
    al[p0] = As + ((p0 * 4 + w) << 9);
    bl[p0] = Bs + ((p0 * 4 + w) << 9);
  }

  f32x4 acc[4][4] = {};
  const int kiters = K >> 5;
  for (int kt = 0; kt < kiters; ++kt) {
#pragma unroll
    for (int p0 = 0; p0 < 2; ++p0) {
      gload16(ap[p0], al[p0]);
      gload16(bp[p0], bl[p0]);
      ap[p0] += 32; bp[p0] += 32;
    }
    __syncthreads();
    const int lr = l & 15, lk = (l >> 4) << 3;
    s16x8 af[4], bfr[4];
#pragma unroll
    for (int m = 0; m < 4; ++m)
      af[m] = *(const s16x8*)(As + ((wr * 64 + m * 16 + lr) << 5) + lk);
#pragma unroll
    for (int n = 0; n < 4; ++n)
      bfr[n] = *(const s16x8*)(Bs + ((wc * 64 + n * 16 + lr) << 5) + lk);
#pragma unroll
    for (int m = 0; m < 4; ++m)
#pragma unroll
      for (int n = 0; n < 4; ++n)
        acc[m][n] = __builtin_amdgcn_mfma_f32_16x16x32_bf16(af[m], bfr[n], acc[m][n], 0, 0, 0);
    __syncthreads();
  }

  float ib = 0.f, fb = 0.f;
  if constexpr (EPI == 3) { ib = sib[0]; fb = sfb[0]; }
  const int row0 = brow + wr * 64 + ((l >> 4) << 2);
  const int col0 = bcol + wc * 64 + (l & 15);
#pragma unroll
  for (int m = 0; m < 4; ++m) {
#pragma unroll
    for (int n = 0; n < 4; ++n) {
      const int col = col0 + n * 16;
      const float bv = bias[col];
#pragma unroll
      for (int j = 0; j < 4; ++j) {
        const int row = row0 + m * 16 + j;
        float x = acc[m][n][j] + bv;
        if constexpr (EPI == 1) x = fmaxf(x, 0.f);
        if constexpr (EPI == 3) {
          x += bf2f(igp[(size_t)(row >> 3) * 2048 + col]);
          x += (col < 1024) ? ib : fb;
          x = 1.f / (1.f + expf(-x));
        }
        C[(size_t)row * N + col] = f2bf(x);
      }
    }
  }
}

// ---------- fused: qkv-LN -> attention -> residual -> LN1 ----------
#define QROW 3080
__global__ void __launch_bounds__(256)
attn_fused(const unsigned short* __restrict__ qkv,
           const float* __restrict__ g3, const float* __restrict__ b3,
           const float* __restrict__ memF,
           const float* __restrict__ g1, const float* __restrict__ b1,
           unsigned short* __restrict__ m1)
{
  __shared__ __align__(16) unsigned short sQ[9 * QROW];
  __shared__ float sS[16][8][12];
  __shared__ __align__(16) unsigned short sAtt[8 * 1024];
  const int b = blockIdx.x;
  const int t = threadIdx.x;
  const int wv = t >> 6, l = t & 63;

  const unsigned short* src = qkv + (size_t)b * (9 * 3072);
  for (int i = t; i < 3456; i += 256) {
    const int r = i / 384;
    const int c = i - r * 384;
    ((uint4*)(sQ + r * QROW))[c] = ((const uint4*)src)[i];
  }
  __syncthreads();

  for (int r = wv; r < 9; r += 4) {
    float s = 0.f, s2 = 0.f;
    for (int i = l; i < 3072; i += 64) {
      const float x = bf2f(sQ[r * QROW + i]); s += x; s2 += x * x;
    }
#pragma unroll
    for (int o = 32; o; o >>= 1) { s += __shfl_xor(s, o); s2 += __shfl_xor(s2, o); }
    const float mean = s * (1.f / 3072.f);
    const float rstd = rsqrtf(s2 * (1.f / 3072.f) - mean * mean + 1e-5f);
    for (int i = l; i < 3072; i += 64) {
      const float x = bf2f(sQ[r * QROW + i]);
      sQ[r * QROW + i] = f2bf((x - mean) * rstd * g3[i] + b3[i]);
    }
  }
  __syncthreads();

  for (int idx = t; idx < 1152; idx += 256) {
    const int h = idx / 72;
    const int rem = idx - h * 72;
    const int n = rem / 9;
    const int m = rem - n * 9;
    const ushort4* q4 = (const ushort4*)(sQ + n * QROW + h * 192);
    const ushort4* k4 = (const ushort4*)(sQ + m * QROW + h * 192 + 64);
    float acc = 0.f;
#pragma unroll
    for (int d = 0; d < 16; ++d) {
      const ushort4 qa = q4[d], ka = k4[d];
      acc += bf2f(qa.x) * bf2f(ka.x) + bf2f(qa.y) * bf2f(ka.y)
           + bf2f(qa.z) * bf2f(ka.z) + bf2f(qa.w) * bf2f(ka.w);
    }
    sS[h][n][m] = acc * 0.125f;
  }
  __syncthreads();

  if (t < 128) {
    const int h = t >> 3, n = t & 7;
    float mx = -1e30f;
#pragma unroll
    for (int m = 0; m < 9; ++m) mx = fmaxf(mx, sS[h][n][m]);
    float p[9]; float sum = 0.f;
#pragma unroll
    for (int m = 0; m < 9; ++m) { p[m] = expf(sS[h][n][m] - mx); sum += p[m]; }
    const float inv = 1.f / sum;
#pragma unroll
    for (int m = 0; m < 9; ++m) sS[h][n][m] = p[m] * inv;
  }
  __syncthreads();

  for (int o4 = t; o4 < 2048; o4 += 256) {
    const int n = o4 >> 8;
    const int rem = o4 & 255;
    const int h = rem >> 4;
    const int d4 = rem & 15;
    float a0 = 0, a1 = 0, a2 = 0, a3 = 0;
#pragma unroll
    for (int m = 0; m < 9; ++m) {
      const float pm = sS[h][n][m];
      const ushort4 vv = *(const ushort4*)(sQ + m * QROW + h * 192 + 128 + d4 * 4);
      a0 += pm * bf2f(vv.x); a1 += pm * bf2f(vv.y); a2 += pm * bf2f(vv.z); a3 += pm * bf2f(vv.w);
    }
    ushort4 ov; ov.x = f2bf(a0); ov.y = f2bf(a1); ov.z = f2bf(a2); ov.w = f2bf(a3);
    ((ushort4*)sAtt)[o4] = ov;
  }
  __syncthreads();

  const float* memb = memF + (size_t)b * 8192;
  for (int n = wv; n < 8; n += 4) {
    float xs[16]; float s = 0.f, s2 = 0.f;
#pragma unroll
    for (int j = 0; j < 16; ++j) {
      const int i = j * 64 + l;
      const float x = memb[n * 1024 + i] + bf2f(sAtt[n * 1024 + i]);
      xs[j] = x; s += x; s2 += x * x;
    }
#pragma unroll
    for (int o = 32; o; o >>= 1) { s += __shfl_xor(s, o); s2 += __shfl_xor(s2, o); }
    const float mean = s * (1.f / 1024.f);
    const float rstd = rsqrtf(s2 * (1.f / 1024.f) - mean * mean + 1e-5f);
    unsigned short* dst = m1 + ((size_t)b * 8 + n) * 1024;
#pragma unroll
    for (int j = 0; j < 16; ++j) {
      const int i = j * 64 + l;
      dst[i] = f2bf((xs[j] - mean) * rstd * g1[i] + b1[i]);
    }
  }
}

// ---------- fused LN2 + gate blend + dual write ----------
__global__ void __launch_bounds__(256)
ln2_final(const unsigned short* __restrict__ m1, const unsigned short* __restrict__ mlp,
          const float* __restrict__ g, const float* __restrict__ bb,
          const unsigned short* __restrict__ sg,   // sigmoided gates [32768][2048]
          const float* __restrict__ memF,
          float* __restrict__ out)
{
  const int row = blockIdx.x, t = threadIdx.x;
  const ushort4 v1 = ((const ushort4*)(m1 + (size_t)row * 1024))[t];
  const ushort4 v2 = ((const ushort4*)(mlp + (size_t)row * 1024))[t];
  const float x0 = bf2f(v1.x) + bf2f(v2.x), x1 = bf2f(v1.y) + bf2f(v2.y),
              x2 = bf2f(v1.z) + bf2f(v2.z), x3 = bf2f(v1.w) + bf2f(v2.w);
  float s = x0 + x1 + x2 + x3;
  float s2 = x0 * x0 + x1 * x1 + x2 * x2 + x3 * x3;
#pragma unroll
  for (int o = 32; o; o >>= 1) { s += __shfl_xor(s, o); s2 += __shfl_xor(s2, o); }
  __shared__ float rs[4], rq[4];
  const int wv = t >> 6, l = t & 63;
  if (l == 0) { rs[wv] = s; rq[wv] = s2; }
  __syncthreads();
  s = rs[0] + rs[1] + rs[2] + rs[3];
  s2 = rq[0] + rq[1] + rq[2] + rq[3];
  const float mean = s * (1.f / 1024.f);
  const float rstd = rsqrtf(s2 * (1.f / 1024.f) - mean * mean + 1e-5f);
  const float4 gv = ((const float4*)g)[t];
  const float4 bv = ((const float4*)bb)[t];
  const float m20 = (x0 - mean) * rstd * gv.x + bv.x;
  const float m21 = (x1 - mean) * rstd * gv.y + bv.y;
  const float m22 = (x2 - mean) * rstd * gv.z + bv.z;
  const float m23 = (x3 - mean) * rstd * gv.w + bv.w;
  const ushort4 iv = ((const ushort4*)(sg + (size_t)row * 2048))[t];
  const ushort4 fv = ((const ushort4*)(sg + (size_t)row * 2048 + 1024))[t];
  const float4 me = ((const float4*)(memF + (size_t)row * 1024))[t];
  float4 r;
  r.x = bf2f(iv.x) * tanhf(m20) + bf2f(fv.x) * me.x;
  r.y = bf2f(iv.y) * tanhf(m21) + bf2f(fv.y) * me.y;
  r.z = bf2f(iv.z) * tanhf(m22) + bf2f(fv.z) * me.z;
  r.w = bf2f(iv.w) * tanhf(m23) + bf2f(fv.w) * me.w;
  ((float4*)out)[(size_t)row * 256 + t] = r;                 // output (B,8192)
  ((float4*)out)[8388608 + (size_t)row * 256 + t] = r;       // next_memory
}

// ---------- launch ----------
extern "C" void kernel_launch(void* const* d_in, const int* in_sizes, int n_in,
                              void* d_out, int out_size, void* d_ws, size_t ws_size,
                              hipStream_t stream) {
  (void)in_sizes; (void)n_in; (void)out_size; (void)ws_size;
  const float* input_vec = (const float*)d_in[0];
  const float* memory    = (const float*)d_in[1];
  const float* qkv_w  = (const float*)d_in[2];
  const float* qkv_b  = (const float*)d_in[3];
  const float* qkvn_g = (const float*)d_in[4];
  const float* qkvn_b = (const float*)d_in[5];
  const float* mlp1_w = (const float*)d_in[6];
  const float* mlp1_b = (const float*)d_in[7];
  const float* mlp2_w = (const float*)d_in[8];
  const float* mlp2_b = (const float*)d_in[9];
  const float* n1_g = (const float*)d_in[10];
  const float* n1_b = (const float*)d_in[11];
  const float* n2_g = (const float*)d_in[12];
  const float* n2_b = (const float*)d_in[13];
  const float* inp_w = (const float*)d_in[14];
  const float* inp_b = (const float*)d_in[15];
  const float* ig_w  = (const float*)d_in[16];
  const float* ig_b  = (const float*)d_in[17];
  const float* mg_w  = (const float*)d_in[18];
  const float* mg_b  = (const float*)d_in[19];
  const float* forget_bias = (const float*)d_in[20];
  const float* input_bias  = (const float*)d_in[21];

  char* p = (char*)d_ws;
  auto carve = [&](size_t bytes) -> void* {
    void* r = (void*)p; p += (bytes + 255) & ~(size_t)255; return r;
  };
  unsigned short* mem_bf  = (unsigned short*)carve(67108864);
  unsigned short* iv_bf   = (unsigned short*)carve(8388608);
  unsigned short* inp_bf  = (unsigned short*)carve(8388608);
  unsigned short* inp_wT  = (unsigned short*)carve(2097152);
  unsigned short* qkv_wT  = (unsigned short*)carve(6291456);
  unsigned short* mlp1_wT = (unsigned short*)carve(2097152);
  unsigned short* mlp2_wT = (unsigned short*)carve(2097152);
  unsigned short* ig_wT   = (unsigned short*)carve(4194304);
  unsigned short* mg_wT   = (unsigned short*)carve(4194304);
  char* big               = (char*)carve(226492416);
  unsigned short* qkv_pre = (unsigned short*)big;               // [36864][3072]
  unsigned short* gates   = (unsigned short*)big;               // later [32768][2048]
  unsigned short* mlp_buf = (unsigned short*)(big + 134217728); // later [32768][1024]
  unsigned short* m1      = (unsigned short*)carve(67108864);
  unsigned short* h_buf   = (unsigned short*)carve(67108864);
  unsigned short* ig_part = (unsigned short*)carve(16777216);

  const dim3 tb(32, 8);
  wtrans_kernel<<<dim3(32, 32), tb, 0, stream>>>(inp_w,  inp_wT,  1024, 1024);
  wtrans_kernel<<<dim3(96, 32), tb, 0, stream>>>(qkv_w,  qkv_wT,  1024, 3072);
  wtrans_kernel<<<dim3(32, 32), tb, 0, stream>>>(mlp1_w, mlp1_wT, 1024, 1024);
  wtrans_kernel<<<dim3(32, 32), tb, 0, stream>>>(mlp2_w, mlp2_wT, 1024, 1024);
  wtrans_kernel<<<dim3(64, 32), tb, 0, stream>>>(ig_w,   ig_wT,   1024, 2048);
  wtrans_kernel<<<dim3(64, 32), tb, 0, stream>>>(mg_w,   mg_wT,   1024, 2048);
  cvt_f32_bf16<<<2048, 256, 0, stream>>>(input_vec, iv_bf, 1048576);
  cvt_f32_bf16<<<2048, 256, 0, stream>>>(memory, mem_bf, 8388608);

  // inp = input_vec @ inp_w + inp_b           (2-phase 128^2, 256 blocks)
  gemm_bt<0, 0><<<256, 256, 0, stream>>>(iv_bf, nullptr, inp_wT, inp_b,
      nullptr, nullptr, nullptr, inp_bf, /*tilesN=*/8, 1024, 1024);
  // qkv_pre = concat(memory, inp) @ qkv_w + qkv_b   (gemm4: 144 x 12 = 1728)
  gemm4<1, 0><<<1728, 512, 0, stream>>>(mem_bf, inp_bf, qkv_wT, qkv_b,
      nullptr, nullptr, nullptr, qkv_pre, /*tilesN=*/12, 3072, 1024);
  // LN(qkv) -> attention -> +memory residual -> LN1 -> m1
  attn_fused<<<4096, 256, 0, stream>>>(qkv_pre, qkvn_g, qkvn_b, memory, n1_g, n1_b, m1);
  // h = relu(m1 @ mlp1_w + mlp1_b)            (gemm4: 128 x 4 = 512)
  gemm4<0, 1><<<512, 512, 0, stream>>>(m1, nullptr, mlp1_wT, mlp1_b,
      nullptr, nullptr, nullptr, h_buf, /*tilesN=*/4, 1024, 1024);
  // mlp = h @ mlp2_w + mlp2_b
  gemm4<0, 0><<<512, 512, 0, stream>>>(h_buf, nullptr, mlp2_wT, mlp2_b,
      nullptr, nullptr, nullptr, mlp_buf, /*tilesN=*/4, 1024, 1024);
  // ig_part = inp @ ig_w + ig_b               (2-phase 128^2, 512 blocks)
  gemm_bt<0, 0><<<512, 256, 0, stream>>>(inp_bf, nullptr, ig_wT, ig_b,
      nullptr, nullptr, nullptr, ig_part, /*tilesN=*/16, 2048, 1024);
  // gates = sigmoid(memory @ mg_w + mg_b + ig_part + sel bias)  (gemm4: 128 x 8 = 1024)
  gemm4<0, 3><<<1024, 512, 0, stream>>>(mem_bf, nullptr, mg_wT, mg_b,
      ig_part, input_bias, forget_bias, gates, /*tilesN=*/8, 2048, 1024);
  // m2 = LN(m1 + mlp); next = i*tanh(m2) + f*memory ; dual write
  ln2_final<<<32768, 256, 0, stream>>>(m1, mlp_buf, n2_g, n2_b, gates, memory, (float*)d_out);
}